// Round 3
// baseline (577.030 us; speedup 1.0000x reference)
//
#include <hip/hip_runtime.h>
#include <cstdint>
#include <cstddef>

#define B_ROWS 8192
#define OUT_N  1024
#define EXC_IN 4096
#define INH_IN 2048
#define K_EXC  32
#define K_INH  16

#define TILE_N       2
#define MAIN_THREADS 1024
#define NBLK         256
#define NT_PER_BLK   (B_ROWS / TILE_N / NBLK)          // 16 tiles per block
#define BUF_FLOATS   ((EXC_IN + INH_IN) * TILE_N)      // 12288 floats = 48 KB
#define BUF_BYTES    (BUF_FLOATS * 4)
#define CHUNKS       (BUF_FLOATS / 64)                 // 192 chunk-instrs per tile
#define CPW          (CHUNKS / (MAIN_THREADS / 64))    // 12 per wave
#define XCHUNKS      (EXC_IN * TILE_N / 64)            // 128 chunks are x, rest inh
#define INH_BASE_B   (EXC_IN * TILE_N * 4)             // 32768 byte base of inh section

// ---------------------------------------------------------------------------
// Top-K: one wave per row, register-resident keys, shuffle-only reduction.
// Output format (changed): vals[k][o] = exp(w) f32, coalesced over o;
// offs[k/2][o] = packed u16 LDS BYTE offsets (idx*8 + bias) for k-pair.
// inh offsets are pre-biased by INH_BASE_B so the main kernel uses one base.
// This lets the main kernel hold all weights in 72 VGPRs, loaded ONCE --
// removing every per-tile global load from the gather path (the r2 failure:
// vmcnt is ORDERED, so consuming any load issued after the next-tile staging
// drains the staging and kills the double-buffer).
// ---------------------------------------------------------------------------
template<int COLS, int K>
__device__ __forceinline__ void topk_row(const float* __restrict__ src,
                                         float* __restrict__ vals,
                                         unsigned int* __restrict__ offs,
                                         unsigned int bias, int lane)
{
    constexpr int E4 = COLS / 256;          // float4 iters per lane
    unsigned long long keys[E4 * 4];
#pragma unroll
    for (int i = 0; i < E4; ++i) {
        const float4 v = ((const float4*)src)[i * 64 + lane];
        const float vv[4] = {v.x, v.y, v.z, v.w};
#pragma unroll
        for (int q = 0; q < 4; ++q) {
            const int idx = (i * 64 + lane) * 4 + q;
            const unsigned int u = __float_as_uint(vv[q]);
            const unsigned int m = (u >> 31) ? ~u : (u | 0x80000000u);
            keys[i * 4 + q] = ((unsigned long long)m << 12)
                            | (unsigned long long)(4095 - idx);
        }
    }

    unsigned long long win = 0xFFFFFFFFFFFFFFFFull;   // matches nothing
    unsigned int prev = 0;
#pragma unroll 1
    for (int r = 0; r < K; ++r) {
        unsigned long long best = 0ull;
#pragma unroll
        for (int i = 0; i < E4 * 4; ++i) {
            const unsigned long long k2 = (keys[i] == win) ? 0ull : keys[i];
            keys[i] = k2;
            best = (k2 > best) ? k2 : best;
        }
#pragma unroll
        for (int m = 1; m < 64; m <<= 1) {
            const unsigned long long o = __shfl_xor(best, m, 64);
            best = (o > best) ? o : best;
        }
        win = best;
        if (lane == 0) {
            const unsigned int idx = 4095u - (unsigned int)(win & 0xFFFull);
            const unsigned int mm  = (unsigned int)(win >> 12);
            const unsigned int u   = (mm & 0x80000000u) ? (mm & 0x7FFFFFFFu) : ~mm;
            const float v = __uint_as_float(u);
            vals[(size_t)r * OUT_N] = expf(v);
            const unsigned int bo = idx * 8u + bias;      // LDS byte offset
            if (r & 1) offs[(size_t)(r >> 1) * OUT_N] = prev | (bo << 16);
            else       prev = bo;
        }
    }
}

__global__ __launch_bounds__(256, 1) void topk_both_kernel(
    const float* __restrict__ pwe, const float* __restrict__ pwi,
    float* __restrict__ valsE, unsigned int* __restrict__ offE,
    float* __restrict__ valsI, unsigned int* __restrict__ offI)
{
    const int wid  = (blockIdx.x * 256 + threadIdx.x) >> 6;   // global wave id
    const int lane = threadIdx.x & 63;
    if (wid < OUT_N) {
        topk_row<EXC_IN, K_EXC>(pwe + (size_t)wid * EXC_IN,
                                valsE + wid, offE + wid, 0u, lane);
    } else {
        const int r = wid - OUT_N;                            // 0..1023
        topk_row<INH_IN, K_INH>(pwi + (size_t)r * INH_IN,
                                valsI + r, offI + r, (unsigned)INH_BASE_B, lane);
    }
}

// ---------------------------------------------------------------------------
// Main kernel, round-3: true double-buffered pipeline.
//  * Weights resident in registers (72 VGPR: 48 f32 vals + 24 packed-u16
//    byte-offset words), loaded once before the tile loop. The gather phase
//    touches ONLY LDS -> consuming it never drains the vmcnt stream.
//  * Per-iter vm order: br(2) -> stage_{t+1}(12) -> vmcnt(14) drains
//    stage_t (+ prior stores) only -> s_barrier -> gather (LDS) -> epilogue
//    waits br at compiler vmcnt(12), stage_{t+1} stays in flight across
//    both barriers. No vmcnt(0) anywhere in the loop.
//  * Persistent: 256 blocks x 16 tiles, 1 block/CU (96 KB LDS), 16 waves.
// Race check: iter t reads buf[t&1], stages buf[(t+1)&1]; buf[t&1] is next
// written by staging ISSUED after the end-of-iter-t barrier; all gather
// ds_reads are consumed (lgkmcnt drained by compiler) before that barrier.
// ---------------------------------------------------------------------------
typedef __attribute__((address_space(1))) const unsigned int gu32_t;
typedef __attribute__((address_space(3))) unsigned int lu32_t;

__global__ __launch_bounds__(MAIN_THREADS, 4) void dendritic_main_kernel(
    const float*  __restrict__ x,
    const float*  __restrict__ inh,
    const float4* __restrict__ branch,   // [B][1024] float4
    const float*  __restrict__ valsE,    // [32][1024]
    const unsigned int* __restrict__ offE, // [16][1024]
    const float*  __restrict__ valsI,    // [16][1024]
    const unsigned int* __restrict__ offI, // [8][1024]
    const float4* __restrict__ wblock,   // [1024]
    const float*  __restrict__ presig,   // [1024]
    const float*  __restrict__ logalpha, // [1024]
    float*        __restrict__ out)      // [B][1024]
{
    __shared__ float sx[2 * BUF_FLOATS];   // 96 KB

    const int tid  = threadIdx.x;
    const int lane = tid & 63;
    const int w    = tid >> 6;             // wave 0..15
    const int o    = tid;                  // one output neuron per thread

    // ---- weights -> registers, once ----
    float vE[K_EXC]; unsigned int oE[K_EXC / 2];
    float vI[K_INH]; unsigned int oI[K_INH / 2];
#pragma unroll
    for (int k = 0; k < K_EXC; ++k)     vE[k] = valsE[(size_t)k * OUT_N + o];
#pragma unroll
    for (int k = 0; k < K_EXC / 2; ++k) oE[k] = offE[(size_t)k * OUT_N + o];
#pragma unroll
    for (int k = 0; k < K_INH; ++k)     vI[k] = valsI[(size_t)k * OUT_N + o];
#pragma unroll
    for (int k = 0; k < K_INH / 2; ++k) oI[k] = offI[(size_t)k * OUT_N + o];

    // ---- per-o constants ----
    const float4 wb   = wblock[o];
    const float cond  = wb.x + wb.y + wb.z + wb.w;
    const float Vth   = 1.f / (1.f + expf(-presig[o]));
    const float alpha = expf(logalpha[o]);

    const int tile0 = blockIdx.x * NT_PER_BLK;
    const int srow  = lane & 1;            // batch row within tile
    const int scol  = lane >> 1;           // column offset within 32-col run

    // ---- staging: 12 global_load_lds per wave; transposed [c][n] layout via
    //      per-lane swizzled SOURCE + linear LDS dest ----
    auto stage = [&](int tile, int bufidx) {
        const int n = tile * TILE_N;
        const float* xs = x   + (size_t)(n + srow) * EXC_IN + scol;
        const float* is = inh + (size_t)(n + srow) * INH_IN + scol;
        float* dst = sx + bufidx * BUF_FLOATS;
#pragma unroll
        for (int i = 0; i < CPW; ++i) {
            const int c = i * 16 + w;
            const float* src = (c < XCHUNKS) ? (xs + c * 32)
                                             : (is + (c - XCHUNKS) * 32);
            __builtin_amdgcn_global_load_lds((gu32_t*)src,
                                             (lu32_t*)(dst + c * 64), 4, 0, 0);
        }
    };

    // ---- prologue: stage tile0 into buf 0 ----
    stage(tile0, 0);

#pragma unroll 1
    for (int t = 0; t < NT_PER_BLK; ++t) {
        const int n0 = (tile0 + t) * TILE_N;

        // (1) branch loads FIRST (older than staging -> epilogue wait leaves
        //     staging in flight)
        const float4 br0 = branch[(size_t)(n0 + 0) * OUT_N + o];
        const float4 br1 = branch[(size_t)(n0 + 1) * OUT_N + o];

        // (2) issue next-tile staging
        if (t + 1 < NT_PER_BLK) stage(tile0 + t + 1, (t + 1) & 1);

        // (3) drain ONLY stage_t (+ prior stores); keep br + stage_{t+1} live.
        //     outstanding (old->new): stage_t(12), stores_{t-1}(2), br(2),
        //     stage_{t+1}(12)  -> leave 14.  Last iter: no stage -> leave 4.
        if (t + 1 < NT_PER_BLK) {
            asm volatile("s_waitcnt vmcnt(14)" ::: "memory");
        } else {
            asm volatile("s_waitcnt vmcnt(4)" ::: "memory");
        }
        __builtin_amdgcn_s_barrier();      // all waves' stage_t now in LDS
        __builtin_amdgcn_sched_barrier(0);

        const char* bufb = (const char*)sx + (size_t)(t & 1) * BUF_BYTES;

        // ---- excitation gather: LDS-only, weights from registers ----
        float e0 = 0.f, e1 = 0.f;
#pragma unroll
        for (int k2 = 0; k2 < K_EXC / 2; ++k2) {
            const unsigned int pw = oE[k2];
            const float2 a = *(const float2*)(bufb + (pw & 0xFFFFu));
            const float2 b = *(const float2*)(bufb + (pw >> 16));
            e0 = fmaf(a.x, vE[2 * k2],     e0);
            e1 = fmaf(a.y, vE[2 * k2],     e1);
            e0 = fmaf(b.x, vE[2 * k2 + 1], e0);
            e1 = fmaf(b.y, vE[2 * k2 + 1], e1);
        }

        // ---- inhibition gather (offsets pre-biased by INH_BASE_B) ----
        float i0 = 0.f, i1 = 0.f;
#pragma unroll
        for (int k2 = 0; k2 < K_INH / 2; ++k2) {
            const unsigned int pw = oI[k2];
            const float2 a = *(const float2*)(bufb + (pw & 0xFFFFu));
            const float2 b = *(const float2*)(bufb + (pw >> 16));
            i0 = fmaf(a.x, vI[2 * k2],     i0);
            i1 = fmaf(a.y, vI[2 * k2],     i1);
            i0 = fmaf(b.x, vI[2 * k2 + 1], i0);
            i1 = fmaf(b.y, vI[2 * k2 + 1], i1);
        }

        // ---- epilogue: branch contraction + voltage + reactivation ----
        {
            const float cur0 = br0.x * wb.x + br0.y * wb.y + br0.z * wb.z + br0.w * wb.w;
            const float cur1 = br1.x * wb.x + br1.y * wb.y + br1.z * wb.z + br1.w * wb.w;
            const float v0 = (e0 + cur0) / (e0 + 1.f + cond + i0);
            const float v1 = (e1 + cur1) / (e1 + 1.f + cond + i1);
            const float d0 = v0 - Vth;
            const float d1 = v1 - Vth;
            const float r0 = alpha * d0 * d0;
            const float r1 = alpha * d1 * d1;
            out[(size_t)(n0 + 0) * OUT_N + o] = (d0 < 0.f) ? 0.f : r0;
            out[(size_t)(n0 + 1) * OUT_N + o] = (d1 < 0.f) ? 0.f : r1;
        }

        __builtin_amdgcn_s_barrier();      // reads of buf[t&1] done before
                                           // iter t+1 overwrites it
    }
}

// ---------------------------------------------------------------------------
extern "C" void kernel_launch(void* const* d_in, const int* in_sizes, int n_in,
                              void* d_out, int out_size, void* d_ws, size_t ws_size,
                              hipStream_t stream)
{
    const float* x      = (const float*)d_in[0];
    const float* inh    = (const float*)d_in[1];
    const float* branch = (const float*)d_in[2];
    const float* pwe    = (const float*)d_in[3];
    const float* pwi    = (const float*)d_in[4];
    const float* wb     = (const float*)d_in[5];
    const float* ps     = (const float*)d_in[6];
    const float* la     = (const float*)d_in[7];
    float* out = (float*)d_out;

    char* ws = (char*)d_ws;
    float*        valsE = (float*)ws;                                  // 128 KB
    unsigned int* offE  = (unsigned int*)(ws + 128 * 1024);            //  64 KB
    float*        valsI = (float*)(ws + 192 * 1024);                   //  64 KB
    unsigned int* offI  = (unsigned int*)(ws + 256 * 1024);            //  32 KB

    // 1024 exc waves + 1024 inh waves, 4 waves/block -> 512 blocks
    topk_both_kernel<<<(2 * OUT_N) / 4, 256, 0, stream>>>(
        pwe, pwi, valsE, offE, valsI, offI);

    dendritic_main_kernel<<<NBLK, MAIN_THREADS, 0, stream>>>(
        x, inh, (const float4*)branch, valsE, offE, valsI, offI,
        (const float4*)wb, ps, la, out);
}